// Round 4
// baseline (104560.352 us; speedup 1.0000x reference)
//
#include <hip/hip_runtime.h>
#include <math.h>

#define Bsz 512
#define Tsz 2048
#define INsz 32
#define Hsz 256

typedef __attribute__((ext_vector_type(8))) _Float16 half8;
typedef __attribute__((ext_vector_type(4))) float f32x4;

__device__ __forceinline__ f32x4 mfma16h(half8 a, half8 b, f32x4 c) {
    return __builtin_amdgcn_mfma_f32_16x16x32_f16(a, b, c, 0, 0, 0);
}
__device__ __forceinline__ float fsigmoid(float x) { return 1.0f / (1.0f + expf(-x)); }

// ---------------- ew0: pure function of x, fully parallel, fp32 ------------
__global__ void ew0k(const float* __restrict__ x, const float* __restrict__ Wev0,
                     const float* __restrict__ bev0, float* __restrict__ ew0p) {
    int idx = blockIdx.x * 256 + threadIdx.x;          // = b*T + t
    int t = idx & (Tsz - 1);
    float e = 0.0f;
    if (t > 0) {
        const float* xc = x + (size_t)idx * INsz;
        const float* xp = xc - INsz;
        float acc = bev0[0];
#pragma unroll
        for (int k = 0; k < INsz; ++k) acc += xc[k] * Wev0[k] + xp[k] * Wev0[INsz + k];
        e = fsigmoid(acc);
    }
    ew0p[idx] = e;
}

// ---------------- weight fragment prep: split-2 fp16 B-fragments ------------
// layout: dst[ ((tile*KC + kc)*2 + split)*512 + lane*8 + j ]
//   lane holds B[n = tile*16 + (lane&15)][k = kc*32 + (lane>>4)*8 + j]
__global__ void prep_frag(const float* __restrict__ W, _Float16* __restrict__ dst, int KC) {
    int tile = blockIdx.x / KC, kc = blockIdx.x % KC;
    int lane = threadIdx.x;
    int n16 = lane & 15, q = lane >> 4;
#pragma unroll
    for (int j = 0; j < 8; ++j) {
        int k = kc * 32 + q * 8 + j;
        float wv = W[(size_t)k * Hsz + tile * 16 + n16];
        _Float16 hi = (_Float16)wv;
        _Float16 lo = (_Float16)(wv - (float)hi);
        size_t rec = ((size_t)tile * KC + kc) * 2;
        dst[(rec + 0) * 512 + lane * 8 + j] = hi;
        dst[(rec + 1) * 512 + lane * 8 + j] = lo;
    }
}

// ---------------- fused persistent recurrence: both layers, all 2048 steps --
__global__ __launch_bounds__(512, 2) void fusedk(
    const float* __restrict__ x, const float* __restrict__ ew0p,
    const _Float16* __restrict__ fA0, const _Float16* __restrict__ fR0, const _Float16* __restrict__ fI0,
    const _Float16* __restrict__ fA1, const _Float16* __restrict__ fR1,
    const _Float16* __restrict__ fI1, const _Float16* __restrict__ fS1,
    const float* __restrict__ bin0, const float* __restrict__ brec0, const float* __restrict__ battn0,
    const float* __restrict__ tau0, const float* __restrict__ gamma0, const float* __restrict__ beta0,
    const float* __restrict__ bin1, const float* __restrict__ brec1, const float* __restrict__ battn1,
    const float* __restrict__ tau1, const float* __restrict__ gamma1, const float* __restrict__ beta1,
    const float* __restrict__ bskip, const float* __restrict__ Wev1, const float* __restrict__ bev1,
    const float* __restrict__ Wout, const float* __restrict__ bout,
    float* __restrict__ ew1p, float* __restrict__ outp) {

    __shared__ _Float16 sh0h[4096], sh0l[4096];   // h0 state (split-2 fp16, A-layout)
    __shared__ _Float16 shgh[4096], shgl[4096];   // gated-h scratch (L0 then L1)
    __shared__ _Float16 sh1h[4096], sh1l[4096];   // h1 state
    __shared__ float red[16][8][2];
    __shared__ float mv[16][2];
    __shared__ float sca[16];

    const int tid = threadIdx.x;
    const int w = tid >> 6, lane = tid & 63;
    const int n16 = lane & 15, q = lane >> 4;
    const int rb = blockIdx.x;
    const int r0 = rb * 16;
    const int c0 = w * 16 + n16, c1 = c0 + 128;

    // per-lane column constants
    float cbi0[2], cbr0[2], cba0[2], ctau0[2], cg0[2], cb0[2];
    float cbi1[2], cbr1[2], cba1[2], ctau1[2], cg1[2], cb1[2], cbs[2];
    float wev1c[2], wev1pv[2], wou[2];
#pragma unroll
    for (int t2 = 0; t2 < 2; ++t2) {
        const int col = t2 ? c1 : c0;
        cbi0[t2] = bin0[col];  cbr0[t2] = brec0[col]; cba0[t2] = battn0[col];
        ctau0[t2] = 0.1f / fminf(fmaxf(tau0[col], 0.1f), 10.0f);
        cg0[t2] = gamma0[col]; cb0[t2] = beta0[col];
        cbi1[t2] = bin1[col];  cbr1[t2] = brec1[col]; cba1[t2] = battn1[col];
        ctau1[t2] = 0.1f / fminf(fmaxf(tau1[col], 0.1f), 10.0f);
        cg1[t2] = gamma1[col]; cb1[t2] = beta1[col];  cbs[t2] = bskip[col];
        wev1c[t2] = Wev1[col]; wev1pv[t2] = Wev1[Hsz + col]; wou[t2] = Wout[col];
    }
    const float sc_bev1 = bev1[0], sc_bout = bout[0];

    {
        int4 z = {0, 0, 0, 0};
        ((int4*)sh0h)[tid] = z; ((int4*)sh0l)[tid] = z;
        ((int4*)shgh)[tid] = z; ((int4*)shgl)[tid] = z;
        ((int4*)sh1h)[tid] = z; ((int4*)sh1l)[tid] = z;
    }
    float h0reg[2][4] = {{0, 0, 0, 0}, {0, 0, 0, 0}};
    float h1reg[2][4] = {{0, 0, 0, 0}, {0, 0, 0, 0}};
    f32x4 pA0 = {0, 0, 0, 0}, pA1 = {0, 0, 0, 0};   // carried attn0 pre-acts
    __syncthreads();

    // split-2 pair write at (row, col), A-layout idx = ((col>>3)*16+row)*8+(col&7)
    auto pw = [&](_Float16* hi, _Float16* lo, int row, int col, float v) {
        int idx = ((col >> 3) * 16 + row) * 8 + (col & 7);
        _Float16 h = (_Float16)v;
        hi[idx] = h;
        lo[idx] = (_Float16)(v - (float)h);
    };
    // split-2 fp16 matmul: D += (Ah+Al)(Bh+Bl), all 4 products, K=256
    auto mm = [&](const _Float16* ah_, const _Float16* al_, const _Float16* fr_,
                  f32x4& a0, f32x4& a1) {
#pragma unroll
        for (int kc = 0; kc < 8; ++kc) {
            half8 ah = *(const half8*)&ah_[((kc * 4 + q) * 16 + n16) * 8];
            half8 al = *(const half8*)&al_[((kc * 4 + q) * 16 + n16) * 8];
            const _Float16* b0 = fr_ + ((w * 8 + kc) * 2) * 512 + lane * 8;
            const _Float16* b1 = fr_ + (((w + 8) * 8 + kc) * 2) * 512 + lane * 8;
            half8 bh0 = *(const half8*)b0, bl0 = *(const half8*)(b0 + 512);
            half8 bh1 = *(const half8*)b1, bl1 = *(const half8*)(b1 + 512);
            a0 = mfma16h(ah, bh0, a0); a1 = mfma16h(ah, bh1, a1);
            a0 = mfma16h(al, bh0, a0); a1 = mfma16h(al, bh1, a1);
            a0 = mfma16h(ah, bl0, a0); a1 = mfma16h(ah, bl1, a1);
            a0 = mfma16h(al, bl0, a0); a1 = mfma16h(al, bl1, a1);
        }
    };
    // shared-A triple matmul: in1, skip, attn0(next step) all consume h0n
    auto mm3 = [&](const _Float16* ah_, const _Float16* al_,
                   const _Float16* f1, const _Float16* f2, const _Float16* f3,
                   f32x4& p0, f32x4& p1, f32x4& s0, f32x4& s1, f32x4& t0_, f32x4& t1_) {
#pragma unroll
        for (int kc = 0; kc < 8; ++kc) {
            half8 ah = *(const half8*)&ah_[((kc * 4 + q) * 16 + n16) * 8];
            half8 al = *(const half8*)&al_[((kc * 4 + q) * 16 + n16) * 8];
            size_t o0 = (size_t)((w * 8 + kc) * 2) * 512 + lane * 8;
            size_t o1 = (size_t)(((w + 8) * 8 + kc) * 2) * 512 + lane * 8;
            half8 bh0 = *(const half8*)(f1 + o0), bl0 = *(const half8*)(f1 + o0 + 512);
            half8 bh1 = *(const half8*)(f1 + o1), bl1 = *(const half8*)(f1 + o1 + 512);
            p0 = mfma16h(ah, bh0, p0); p1 = mfma16h(ah, bh1, p1);
            p0 = mfma16h(al, bh0, p0); p1 = mfma16h(al, bh1, p1);
            p0 = mfma16h(ah, bl0, p0); p1 = mfma16h(ah, bl1, p1);
            p0 = mfma16h(al, bl0, p0); p1 = mfma16h(al, bl1, p1);
            half8 ch0 = *(const half8*)(f2 + o0), cl0 = *(const half8*)(f2 + o0 + 512);
            half8 ch1 = *(const half8*)(f2 + o1), cl1 = *(const half8*)(f2 + o1 + 512);
            s0 = mfma16h(ah, ch0, s0); s1 = mfma16h(ah, ch1, s1);
            s0 = mfma16h(al, ch0, s0); s1 = mfma16h(al, ch1, s1);
            s0 = mfma16h(ah, cl0, s0); s1 = mfma16h(ah, cl1, s1);
            s0 = mfma16h(al, cl0, s0); s1 = mfma16h(al, cl1, s1);
            half8 dh0 = *(const half8*)(f3 + o0), dl0 = *(const half8*)(f3 + o0 + 512);
            half8 dh1 = *(const half8*)(f3 + o1), dl1 = *(const half8*)(f3 + o1 + 512);
            t0_ = mfma16h(ah, dh0, t0_); t1_ = mfma16h(ah, dh1, t1_);
            t0_ = mfma16h(al, dh0, t0_); t1_ = mfma16h(al, dh1, t1_);
            t0_ = mfma16h(ah, dl0, t0_); t1_ = mfma16h(ah, dl1, t1_);
            t0_ = mfma16h(al, dl0, t0_); t1_ = mfma16h(al, dl1, t1_);
        }
    };

    const float* xbase = x + (size_t)(r0 + n16) * Tsz * INsz;

#pragma unroll 1
    for (int t = 0; t < Tsz; ++t) {
        // ---------- layer 0 ----------
        // inp = tanh(x@Win0 + b): split-2 fp16 x, K=32
        half8 xh, xl;
        {
            const float* xp = xbase + (size_t)t * INsz + q * 8;
            float4 v0 = *(const float4*)xp;
            float4 v1 = *(const float4*)(xp + 4);
            float xv[8] = {v0.x, v0.y, v0.z, v0.w, v1.x, v1.y, v1.z, v1.w};
#pragma unroll
            for (int j = 0; j < 8; ++j) {
                _Float16 h = (_Float16)xv[j];
                xh[j] = h;
                xl[j] = (_Float16)(xv[j] - (float)h);
            }
        }
        f32x4 aI0 = {0, 0, 0, 0}, aI1 = {0, 0, 0, 0};
        {
            const _Float16* b0 = fI0 + (w * 2) * 512 + lane * 8;
            const _Float16* b1 = fI0 + ((w + 8) * 2) * 512 + lane * 8;
            half8 ih0 = *(const half8*)b0, il0 = *(const half8*)(b0 + 512);
            half8 ih1 = *(const half8*)b1, il1 = *(const half8*)(b1 + 512);
            aI0 = mfma16h(xh, ih0, aI0); aI1 = mfma16h(xh, ih1, aI1);
            aI0 = mfma16h(xl, ih0, aI0); aI1 = mfma16h(xl, ih1, aI1);
            aI0 = mfma16h(xh, il0, aI0); aI1 = mfma16h(xh, il1, aI1);
            aI0 = mfma16h(xl, il0, aI0); aI1 = mfma16h(xl, il1, aI1);
        }
        // gate0: attn0 pre-acts were computed last step in mm3 (pA); at t=0 h0reg=0
#pragma unroll
        for (int r = 0; r < 4; ++r) {
            const int row = q * 4 + r;
            float a0 = fsigmoid(pA0[r] + cba0[0]);
            float a1 = fsigmoid(pA1[r] + cba0[1]);
            pw(shgh, shgl, row, c0, h0reg[0][r] * a0);
            pw(shgh, shgl, row, c1, h0reg[1][r] * a1);
        }
        __syncthreads();   // B1: hg0 complete
        f32x4 aR0 = {0, 0, 0, 0}, aR1 = {0, 0, 0, 0};
        mm(shgh, shgl, fR0, aR0, aR1);
        float e0r[4];
#pragma unroll
        for (int r = 0; r < 4; ++r)
            e0r[r] = ew0p[(size_t)(r0 + q * 4 + r) * Tsz + t];
        float cell[2][4];
#pragma unroll
        for (int r = 0; r < 4; ++r) {
            float i0 = tanhf(aI0[r] + cbi0[0]);
            float i1 = tanhf(aI1[r] + cbi0[1]);
            float g0 = tanhf(aR0[r] + cbr0[0]);
            float g1 = tanhf(aR1[r] + cbr0[1]);
            float ef = 1.0f + e0r[r];
            cell[0][r] = h0reg[0][r] + ctau0[0] * ef * (i0 + g0 - h0reg[0][r]);
            cell[1][r] = h0reg[1][r] + ctau0[1] * ef * (i1 + g1 - h0reg[1][r]);
        }
#pragma unroll
        for (int r = 0; r < 4; ++r) {
            float pr = cell[0][r] + cell[1][r];
            float p2 = cell[0][r] * cell[0][r] + cell[1][r] * cell[1][r];
#pragma unroll
            for (int off = 1; off < 16; off <<= 1) {
                pr += __shfl_xor(pr, off, 64);
                p2 += __shfl_xor(p2, off, 64);
            }
            if (n16 == 0) { red[q * 4 + r][w][0] = pr; red[q * 4 + r][w][1] = p2; }
        }
        __syncthreads();   // B2
        if (tid < 16) {
            float S = 0.0f, Q2 = 0.0f;
#pragma unroll
            for (int wv = 0; wv < 8; ++wv) { S += red[tid][wv][0]; Q2 += red[tid][wv][1]; }
            float mu = S * (1.0f / 256.0f);
            float var = Q2 * (1.0f / 256.0f) - mu * mu;
            mv[tid][0] = mu;
            mv[tid][1] = 1.0f / sqrtf(var + 1e-5f);
        }
        __syncthreads();   // B3
        float h0n_[2][4];
#pragma unroll
        for (int r = 0; r < 4; ++r) {
            const int row = q * 4 + r;
            h0n_[0][r] = (cell[0][r] - mv[row][0]) * mv[row][1] * cg0[0] + cb0[0];
            h0n_[1][r] = (cell[1][r] - mv[row][0]) * mv[row][1] * cg0[1] + cb0[1];
            pw(sh0h, sh0l, row, c0, h0n_[0][r]);
            pw(sh0h, sh0l, row, c1, h0n_[1][r]);
            float p = h0n_[0][r] * wev1c[0] + h0n_[1][r] * wev1c[1]
                    + h0reg[0][r] * wev1pv[0] + h0reg[1][r] * wev1pv[1];
#pragma unroll
            for (int off = 1; off < 16; off <<= 1) p += __shfl_xor(p, off, 64);
            if (n16 == 0) red[row][w][0] = p;
        }
#pragma unroll
        for (int r = 0; r < 4; ++r) { h0reg[0][r] = h0n_[0][r]; h0reg[1][r] = h0n_[1][r]; }
        __syncthreads();   // B4: h0n pair + ew1 partials published
        if (tid < 16) {
            float S = sc_bev1;
#pragma unroll
            for (int wv = 0; wv < 8; ++wv) S += red[tid][wv][0];
            float e = (t > 0) ? fsigmoid(S) : 0.0f;
            sca[tid] = e;
            ew1p[(size_t)(r0 + tid) * Tsz + t] = e;
        }
        // ---------- layer 1 ----------
        f32x4 bA0 = {0, 0, 0, 0}, bA1 = {0, 0, 0, 0};
        mm(sh1h, sh1l, fA1, bA0, bA1);                    // attn1: h1_{t-1}
        f32x4 bI0 = {0, 0, 0, 0}, bI1 = {0, 0, 0, 0};
        f32x4 bS0 = {0, 0, 0, 0}, bS1 = {0, 0, 0, 0};
        f32x4 nA0 = {0, 0, 0, 0}, nA1 = {0, 0, 0, 0};
        mm3(sh0h, sh0l, fI1, fS1, fA0, bI0, bI1, bS0, bS1, nA0, nA1);  // A = h0n_t
        __syncthreads();   // B5: sca valid
        float ef1[4];
#pragma unroll
        for (int r = 0; r < 4; ++r) {
            const int row = q * 4 + r;
            ef1[r] = 1.0f + sca[row];
            float a0 = fsigmoid(bA0[r] + cba1[0]);
            float a1 = fsigmoid(bA1[r] + cba1[1]);
            pw(shgh, shgl, row, c0, h1reg[0][r] * a0);
            pw(shgh, shgl, row, c1, h1reg[1][r] * a1);
        }
        __syncthreads();   // B6
        f32x4 bR0 = {0, 0, 0, 0}, bR1 = {0, 0, 0, 0};
        mm(shgh, shgl, fR1, bR0, bR1);
        float cell1[2][4];
#pragma unroll
        for (int r = 0; r < 4; ++r) {
            float i0 = tanhf(bI0[r] + cbi1[0]);
            float i1 = tanhf(bI1[r] + cbi1[1]);
            float g0 = tanhf(bR0[r] + cbr1[0]);
            float g1 = tanhf(bR1[r] + cbr1[1]);
            cell1[0][r] = h1reg[0][r] + ctau1[0] * ef1[r] * (i0 + g0 - h1reg[0][r]);
            cell1[1][r] = h1reg[1][r] + ctau1[1] * ef1[r] * (i1 + g1 - h1reg[1][r]);
        }
#pragma unroll
        for (int r = 0; r < 4; ++r) {
            float pr = cell1[0][r] + cell1[1][r];
            float p2 = cell1[0][r] * cell1[0][r] + cell1[1][r] * cell1[1][r];
#pragma unroll
            for (int off = 1; off < 16; off <<= 1) {
                pr += __shfl_xor(pr, off, 64);
                p2 += __shfl_xor(p2, off, 64);
            }
            if (n16 == 0) { red[q * 4 + r][w][0] = pr; red[q * 4 + r][w][1] = p2; }
        }
        __syncthreads();   // B7
        if (tid < 16) {
            float S = 0.0f, Q2 = 0.0f;
#pragma unroll
            for (int wv = 0; wv < 8; ++wv) { S += red[tid][wv][0]; Q2 += red[tid][wv][1]; }
            float mu = S * (1.0f / 256.0f);
            float var = Q2 * (1.0f / 256.0f) - mu * mu;
            mv[tid][0] = mu;
            mv[tid][1] = 1.0f / sqrtf(var + 1e-5f);
        }
        __syncthreads();   // B8
#pragma unroll
        for (int r = 0; r < 4; ++r) {
            const int row = q * 4 + r;
            float h0v = (cell1[0][r] - mv[row][0]) * mv[row][1] * cg1[0] + cb1[0] + (bS0[r] + cbs[0]);
            float h1v = (cell1[1][r] - mv[row][0]) * mv[row][1] * cg1[1] + cb1[1] + (bS1[r] + cbs[1]);
            pw(sh1h, sh1l, row, c0, h0v);
            pw(sh1h, sh1l, row, c1, h1v);
            h1reg[0][r] = h0v;
            h1reg[1][r] = h1v;
        }
        pA0 = nA0; pA1 = nA1;
        // sh1 writes here are separated from next step's attn1 reads by B1..B4(t+1)
    }

    // ---------- out = h1_final @ Wout + bout ----------
#pragma unroll
    for (int r = 0; r < 4; ++r) {
        float p = h1reg[0][r] * wou[0] + h1reg[1][r] * wou[1];
#pragma unroll
        for (int off = 1; off < 16; off <<= 1) p += __shfl_xor(p, off, 64);
        if (n16 == 0) red[q * 4 + r][w][0] = p;
    }
    __syncthreads();
    if (tid < 16) {
        float S = sc_bout;
#pragma unroll
        for (int wv = 0; wv < 8; ++wv) S += red[tid][wv][0];
        outp[r0 + tid] = S;
    }
}

extern "C" void kernel_launch(void* const* d_in, const int* in_sizes, int n_in,
                              void* d_out, int out_size, void* d_ws, size_t ws_size,
                              hipStream_t stream) {
    const float* x      = (const float*)d_in[0];
    const float* Win0   = (const float*)d_in[1];
    const float* bin0   = (const float*)d_in[2];
    const float* Wrec0  = (const float*)d_in[3];
    const float* brec0  = (const float*)d_in[4];
    const float* Wattn0 = (const float*)d_in[5];
    const float* battn0 = (const float*)d_in[6];
    const float* Wev0   = (const float*)d_in[7];
    const float* bev0   = (const float*)d_in[8];
    const float* tau0   = (const float*)d_in[9];
    const float* gamma0 = (const float*)d_in[10];
    const float* beta0  = (const float*)d_in[11];
    const float* Win1   = (const float*)d_in[12];
    const float* bin1   = (const float*)d_in[13];
    const float* Wrec1  = (const float*)d_in[14];
    const float* brec1  = (const float*)d_in[15];
    const float* Wattn1 = (const float*)d_in[16];
    const float* battn1 = (const float*)d_in[17];
    const float* Wev1   = (const float*)d_in[18];
    const float* bev1   = (const float*)d_in[19];
    const float* tau1   = (const float*)d_in[20];
    const float* gamma1 = (const float*)d_in[21];
    const float* beta1  = (const float*)d_in[22];
    const float* Wskip  = (const float*)d_in[23];
    const float* bskip  = (const float*)d_in[24];
    const float* Wout   = (const float*)d_in[25];
    const float* bout   = (const float*)d_in[26];

    float* outp = (float*)d_out;
    float* ew0p = outp + Bsz;                       // ew0 [B,T]
    float* ew1p = ew0p + (size_t)Bsz * Tsz;         // ew1 [B,T]

    // workspace: split-2 fp16 weight fragments (~1.6 MB)
    _Float16* p = (_Float16*)d_ws;
    _Float16* fA0 = p; p += 131072;   // 16*8*2*512
    _Float16* fR0 = p; p += 131072;
    _Float16* fA1 = p; p += 131072;
    _Float16* fR1 = p; p += 131072;
    _Float16* fI1 = p; p += 131072;
    _Float16* fS1 = p; p += 131072;
    _Float16* fI0 = p; p += 16384;    // 16*1*2*512
    (void)ws_size; (void)in_sizes; (void)n_in; (void)out_size;

    ew0k<<<(Bsz * Tsz) / 256, 256, 0, stream>>>(x, Wev0, bev0, ew0p);
    prep_frag<<<16 * 8, 64, 0, stream>>>(Wattn0, fA0, 8);
    prep_frag<<<16 * 8, 64, 0, stream>>>(Wrec0,  fR0, 8);
    prep_frag<<<16 * 8, 64, 0, stream>>>(Wattn1, fA1, 8);
    prep_frag<<<16 * 8, 64, 0, stream>>>(Wrec1,  fR1, 8);
    prep_frag<<<16 * 8, 64, 0, stream>>>(Win1,   fI1, 8);
    prep_frag<<<16 * 8, 64, 0, stream>>>(Wskip,  fS1, 8);
    prep_frag<<<16 * 1, 64, 0, stream>>>(Win0,   fI0, 1);

    fusedk<<<32, 512, 0, stream>>>(
        x, ew0p, fA0, fR0, fI0, fA1, fR1, fI1, fS1,
        bin0, brec0, battn0, tau0, gamma0, beta0,
        bin1, brec1, battn1, tau1, gamma1, beta1,
        bskip, Wev1, bev1, Wout, bout, ew1p, outp);
}

// Round 5
// 37037.784 us; speedup vs baseline: 2.8231x; 2.8231x over previous
//
#include <hip/hip_runtime.h>
#include <math.h>

#define Bsz 512
#define Tsz 2048
#define INsz 32
#define Hsz 256

typedef __attribute__((ext_vector_type(8))) _Float16 half8;
typedef __attribute__((ext_vector_type(4))) float f32x4;

__device__ __forceinline__ f32x4 mfma16h(half8 a, half8 b, f32x4 c) {
    return __builtin_amdgcn_mfma_f32_16x16x32_f16(a, b, c, 0, 0, 0);
}
__device__ __forceinline__ float fsigmoid(float x) { return 1.0f / (1.0f + expf(-x)); }

// ---------------- ew0: pure function of x, fully parallel, fp32 ------------
__global__ void ew0k(const float* __restrict__ x, const float* __restrict__ Wev0,
                     const float* __restrict__ bev0, float* __restrict__ ew0p) {
    int idx = blockIdx.x * 256 + threadIdx.x;          // = b*T + t
    int t = idx & (Tsz - 1);
    float e = 0.0f;
    if (t > 0) {
        const float* xc = x + (size_t)idx * INsz;
        const float* xp = xc - INsz;
        float acc = bev0[0];
#pragma unroll
        for (int k = 0; k < INsz; ++k) acc += xc[k] * Wev0[k] + xp[k] * Wev0[INsz + k];
        e = fsigmoid(acc);
    }
    ew0p[idx] = e;
}

// ---------------- weight fragment prep: split-2 fp16 B-fragments ------------
// layout: dst[ ((tile*KC + kc)*2 + split)*512 + lane*8 + j ]
__global__ void prep_frag(const float* __restrict__ W, _Float16* __restrict__ dst, int KC) {
    int tile = blockIdx.x / KC, kc = blockIdx.x % KC;
    int lane = threadIdx.x;
    int n16 = lane & 15, q = lane >> 4;
#pragma unroll
    for (int j = 0; j < 8; ++j) {
        int k = kc * 32 + q * 8 + j;
        float wv = W[(size_t)k * Hsz + tile * 16 + n16];
        _Float16 hi = (_Float16)wv;
        _Float16 lo = (_Float16)(wv - (float)hi);
        size_t rec = ((size_t)tile * KC + kc) * 2;
        dst[(rec + 0) * 512 + lane * 8 + j] = hi;
        dst[(rec + 1) * 512 + lane * 8 + j] = lo;
    }
}

// ---------------- k0: layer-0 recurrence, persistent 32 blocks --------------
// h0n slot layout (split-2): slot s, rb: [hi 4096 halfs][lo 4096 halfs]
__global__ __launch_bounds__(512, 2) void k0(
    const float* __restrict__ x, const float* __restrict__ ew0p,
    const _Float16* __restrict__ fA0, const _Float16* __restrict__ fR0,
    const _Float16* __restrict__ fI0,
    const float* __restrict__ bin0, const float* __restrict__ brec0,
    const float* __restrict__ battn0, const float* __restrict__ tau0,
    const float* __restrict__ gamma0, const float* __restrict__ beta0,
    _Float16* __restrict__ h0n, int C, int t0) {

    __shared__ _Float16 sAh[4096], sAl[4096];   // h0n_{t-1} / gated-h (reused)
    __shared__ _Float16 sW[65536];              // fA0 hi plane, 128 KB
    __shared__ float red[16][8][2];
    __shared__ float mv[16][2];

    const int tid = threadIdx.x;
    const int w = tid >> 6, lane = tid & 63;
    const int n16 = lane & 15, q = lane >> 4;
    const int rb = blockIdx.x;
    const int r0 = rb * 16;
    const int c0 = w * 16 + n16, c1 = c0 + 128;

    // fA0 hi plane -> LDS (global rec r hi at (r*2+0)*512, 64 int4 per rec)
    for (int i = tid; i < 8192; i += 512) {
        int rec = i >> 6, off = i & 63;
        ((int4*)sW)[i] = ((const int4*)(fA0 + (size_t)rec * 2 * 512))[off];
    }
    // fR0 split-2 -> registers (2 tiles per wave)
    half8 rB[2][8][2];
#pragma unroll
    for (int t2 = 0; t2 < 2; ++t2) {
        const int tile = t2 ? w + 8 : w;
#pragma unroll
        for (int kc = 0; kc < 8; ++kc) {
#pragma unroll
            for (int sp = 0; sp < 2; ++sp)
                rB[t2][kc][sp] = *(const half8*)(fR0 + (((size_t)tile * 8 + kc) * 2 + sp) * 512 + lane * 8);
        }
    }
    half8 iB[2][2];
#pragma unroll
    for (int t2 = 0; t2 < 2; ++t2) {
        const int tile = t2 ? w + 8 : w;
#pragma unroll
        for (int sp = 0; sp < 2; ++sp)
            iB[t2][sp] = *(const half8*)(fI0 + ((size_t)tile * 2 + sp) * 512 + lane * 8);
    }
    float cbi[2], cbr[2], cba[2], ctau[2], cg[2], cb[2];
#pragma unroll
    for (int t2 = 0; t2 < 2; ++t2) {
        const int col = t2 ? c1 : c0;
        cbi[t2] = bin0[col]; cbr[t2] = brec0[col]; cba[t2] = battn0[col];
        ctau[t2] = 0.1f / fminf(fmaxf(tau0[col], 0.1f), 10.0f);
        cg[t2] = gamma0[col]; cb[t2] = beta0[col];
    }
    // init: slot C = h0 state at t0-1 (zeroed before chunk 0); copy to slot 0
    {
        const int4* src = (const int4*)(h0n + ((size_t)C * 32 + rb) * 8192);
        int4 vh = src[tid], vl = src[tid + 512];
        ((int4*)sAh)[tid] = vh; ((int4*)sAl)[tid] = vl;
        int4* dst0 = (int4*)(h0n + (size_t)rb * 8192);
        dst0[tid] = vh; dst0[tid + 512] = vl;
    }
    __syncthreads();
    float h0reg[2][4];
#pragma unroll
    for (int t2 = 0; t2 < 2; ++t2) {
        const int col = t2 ? c1 : c0;
#pragma unroll
        for (int r = 0; r < 4; ++r) {
            int idx = ((col >> 3) * 16 + (q * 4 + r)) * 8 + (col & 7);
            h0reg[t2][r] = (float)sAh[idx] + (float)sAl[idx];
        }
    }

    auto pw = [&](int row, int col, float v) {
        int idx = ((col >> 3) * 16 + row) * 8 + (col & 7);
        _Float16 h = (_Float16)v;
        sAh[idx] = h;
        sAl[idx] = (_Float16)(v - (float)h);
    };

    const float* xbase = x + (size_t)(r0 + n16) * Tsz * INsz;
    const _Float16* lo0 = fA0 + ((size_t)w * 8 * 2 + 1) * 512 + lane * 8;         // tile w, kc stride 2*512
    const _Float16* lo1 = fA0 + (((size_t)(w + 8) * 8) * 2 + 1) * 512 + lane * 8; // tile w+8

#pragma unroll 1
    for (int s = 0; s < C; ++s) {
        const int t = t0 + s;
        // early loads: ew0, x
        float e0r[4];
#pragma unroll
        for (int r = 0; r < 4; ++r)
            e0r[r] = ew0p[(size_t)(r0 + q * 4 + r) * Tsz + t];
        half8 xh, xl;
        {
            const float* xp = xbase + (size_t)t * INsz + q * 8;
            float4 v0 = *(const float4*)xp;
            float4 v1 = *(const float4*)(xp + 4);
            float xv[8] = {v0.x, v0.y, v0.z, v0.w, v1.x, v1.y, v1.z, v1.w};
#pragma unroll
            for (int j = 0; j < 8; ++j) {
                _Float16 h = (_Float16)xv[j];
                xh[j] = h;
                xl[j] = (_Float16)(xv[j] - (float)h);
            }
        }
        // ---- mm_attn: A = sA pair (h0n_{t-1}), Bhi = LDS, Blo streamed ----
        f32x4 aA0 = {0,0,0,0}, aA1 = {0,0,0,0};
        {
            half8 nl0 = *(const half8*)(lo0);
            half8 nl1 = *(const half8*)(lo1);
#pragma unroll
            for (int kc = 0; kc < 8; ++kc) {
                half8 cl0 = nl0, cl1 = nl1;
                if (kc < 7) {
                    nl0 = *(const half8*)(lo0 + (size_t)(kc + 1) * 2 * 512);
                    nl1 = *(const half8*)(lo1 + (size_t)(kc + 1) * 2 * 512);
                }
                half8 ah = *(const half8*)&sAh[((kc * 4 + q) * 16 + n16) * 8];
                half8 al = *(const half8*)&sAl[((kc * 4 + q) * 16 + n16) * 8];
                half8 bh0 = *(const half8*)&sW[((w * 8 + kc) * 512) + lane * 8];
                half8 bh1 = *(const half8*)&sW[(((w + 8) * 8 + kc) * 512) + lane * 8];
                aA0 = mfma16h(ah, bh0, aA0); aA1 = mfma16h(ah, bh1, aA1);
                aA0 = mfma16h(al, bh0, aA0); aA1 = mfma16h(al, bh1, aA1);
                aA0 = mfma16h(ah, cl0, aA0); aA1 = mfma16h(ah, cl1, aA1);
                aA0 = mfma16h(al, cl0, aA0); aA1 = mfma16h(al, cl1, aA1);
            }
        }
        // ---- inp = x @ Win0 (registers) ----
        f32x4 aI0 = {0,0,0,0}, aI1 = {0,0,0,0};
        aI0 = mfma16h(xh, iB[0][0], aI0); aI1 = mfma16h(xh, iB[1][0], aI1);
        aI0 = mfma16h(xl, iB[0][0], aI0); aI1 = mfma16h(xl, iB[1][0], aI1);
        aI0 = mfma16h(xh, iB[0][1], aI0); aI1 = mfma16h(xh, iB[1][1], aI1);
        aI0 = mfma16h(xl, iB[0][1], aI0); aI1 = mfma16h(xl, iB[1][1], aI1);
        __syncthreads();   // B1: mm_attn LDS reads complete
        // gate: overwrite sA with h0*sigmoid(attn)
#pragma unroll
        for (int r = 0; r < 4; ++r) {
            const int row = q * 4 + r;
            pw(row, c0, h0reg[0][r] * fsigmoid(aA0[r] + cba[0]));
            pw(row, c1, h0reg[1][r] * fsigmoid(aA1[r] + cba[1]));
        }
        __syncthreads();   // B2
        // ---- mm_rec: A = gated pair, B = registers ----
        f32x4 aR0 = {0,0,0,0}, aR1 = {0,0,0,0};
#pragma unroll
        for (int kc = 0; kc < 8; ++kc) {
            half8 ah = *(const half8*)&sAh[((kc * 4 + q) * 16 + n16) * 8];
            half8 al = *(const half8*)&sAl[((kc * 4 + q) * 16 + n16) * 8];
            aR0 = mfma16h(ah, rB[0][kc][0], aR0); aR1 = mfma16h(ah, rB[1][kc][0], aR1);
            aR0 = mfma16h(al, rB[0][kc][0], aR0); aR1 = mfma16h(al, rB[1][kc][0], aR1);
            aR0 = mfma16h(ah, rB[0][kc][1], aR0); aR1 = mfma16h(ah, rB[1][kc][1], aR1);
            aR0 = mfma16h(al, rB[0][kc][1], aR0); aR1 = mfma16h(al, rB[1][kc][1], aR1);
        }
        float cell[2][4];
#pragma unroll
        for (int r = 0; r < 4; ++r) {
            float i0 = tanhf(aI0[r] + cbi[0]);
            float i1 = tanhf(aI1[r] + cbi[1]);
            float g0 = tanhf(aR0[r] + cbr[0]);
            float g1 = tanhf(aR1[r] + cbr[1]);
            float ef = 1.0f + e0r[r];
            cell[0][r] = h0reg[0][r] + ctau[0] * ef * (i0 + g0 - h0reg[0][r]);
            cell[1][r] = h0reg[1][r] + ctau[1] * ef * (i1 + g1 - h0reg[1][r]);
        }
#pragma unroll
        for (int r = 0; r < 4; ++r) {
            float pr = cell[0][r] + cell[1][r];
            float p2 = cell[0][r] * cell[0][r] + cell[1][r] * cell[1][r];
#pragma unroll
            for (int off = 1; off < 16; off <<= 1) {
                pr += __shfl_xor(pr, off, 64);
                p2 += __shfl_xor(p2, off, 64);
            }
            if (n16 == 0) { red[q * 4 + r][w][0] = pr; red[q * 4 + r][w][1] = p2; }
        }
        __syncthreads();   // B3
        if (tid < 16) {
            float S = 0.0f, Q2 = 0.0f;
#pragma unroll
            for (int wv = 0; wv < 8; ++wv) { S += red[tid][wv][0]; Q2 += red[tid][wv][1]; }
            float mu = S * (1.0f / 256.0f);
            float var = Q2 * (1.0f / 256.0f) - mu * mu;
            mv[tid][0] = mu;
            mv[tid][1] = 1.0f / sqrtf(var + 1e-5f);
        }
        __syncthreads();   // B4
#pragma unroll
        for (int r = 0; r < 4; ++r) {
            const int row = q * 4 + r;
            float h0v = (cell[0][r] - mv[row][0]) * mv[row][1] * cg[0] + cb[0];
            float h1v = (cell[1][r] - mv[row][0]) * mv[row][1] * cg[1] + cb[1];
            pw(row, c0, h0v); pw(row, c1, h1v);
            h0reg[0][r] = h0v; h0reg[1][r] = h1v;
        }
        __syncthreads();   // B5: sA = h0n_t
        int4* d = (int4*)(h0n + ((size_t)(s + 1) * 32 + rb) * 8192);
        d[tid] = ((const int4*)sAh)[tid];
        d[tid + 512] = ((const int4*)sAl)[tid];
    }
}

// ---------------- kb: in1 = tanh(h0n@Win1+b), skip = h0n@Wskip+b (parallel) -
__global__ __launch_bounds__(512, 2) void kb(
    const _Float16* __restrict__ h0n, const _Float16* __restrict__ fI1,
    const _Float16* __restrict__ fS1, const float* __restrict__ bin1,
    const float* __restrict__ bskip, float* __restrict__ in1b,
    float* __restrict__ skpb, int C) {
    const int tid = threadIdx.x;
    const int w = tid >> 6, lane = tid & 63;
    const int n16 = lane & 15, q = lane >> 4;
    const int bi = blockIdx.x;
    const int sbase = (bi >> 5) * 8;
    const int rb = bi & 31;
    const int r0 = rb * 16;
    const int c0 = w * 16 + n16, c1 = c0 + 128;
    float cbi[2], cbs[2];
#pragma unroll
    for (int t2 = 0; t2 < 2; ++t2) {
        const int col = t2 ? c1 : c0;
        cbi[t2] = bin1[col]; cbs[t2] = bskip[col];
    }
    for (int i = 0; i < 8; ++i) {
        const int s = sbase + i;
        const _Float16* abase = h0n + ((size_t)(s + 1) * 32 + rb) * 8192;
        f32x4 aI0 = {0,0,0,0}, aI1 = {0,0,0,0}, aS0 = {0,0,0,0}, aS1 = {0,0,0,0};
#pragma unroll
        for (int kc = 0; kc < 8; ++kc) {
            half8 ah = *(const half8*)&abase[((kc * 4 + q) * 16 + n16) * 8];
            half8 al = *(const half8*)&abase[4096 + ((kc * 4 + q) * 16 + n16) * 8];
            size_t o0 = (((size_t)w * 8 + kc) * 2) * 512 + lane * 8;
            size_t o1 = (((size_t)(w + 8) * 8 + kc) * 2) * 512 + lane * 8;
            half8 bh0 = *(const half8*)(fI1 + o0), bl0 = *(const half8*)(fI1 + o0 + 512);
            half8 bh1 = *(const half8*)(fI1 + o1), bl1 = *(const half8*)(fI1 + o1 + 512);
            aI0 = mfma16h(ah, bh0, aI0); aI1 = mfma16h(ah, bh1, aI1);
            aI0 = mfma16h(al, bh0, aI0); aI1 = mfma16h(al, bh1, aI1);
            aI0 = mfma16h(ah, bl0, aI0); aI1 = mfma16h(ah, bl1, aI1);
            aI0 = mfma16h(al, bl0, aI0); aI1 = mfma16h(al, bl1, aI1);
            half8 ch0 = *(const half8*)(fS1 + o0), cl0 = *(const half8*)(fS1 + o0 + 512);
            half8 ch1 = *(const half8*)(fS1 + o1), cl1 = *(const half8*)(fS1 + o1 + 512);
            aS0 = mfma16h(ah, ch0, aS0); aS1 = mfma16h(ah, ch1, aS1);
            aS0 = mfma16h(al, ch0, aS0); aS1 = mfma16h(al, ch1, aS1);
            aS0 = mfma16h(ah, cl0, aS0); aS1 = mfma16h(ah, cl1, aS1);
            aS0 = mfma16h(al, cl0, aS0); aS1 = mfma16h(al, cl1, aS1);
        }
#pragma unroll
        for (int r = 0; r < 4; ++r) {
            const int row = q * 4 + r;
            size_t i0 = ((size_t)s * Bsz + r0 + row) * Hsz + c0;
            size_t i1 = ((size_t)s * Bsz + r0 + row) * Hsz + c1;
            in1b[i0] = tanhf(aI0[r] + cbi[0]);
            in1b[i1] = tanhf(aI1[r] + cbi[1]);
            skpb[i0] = aS0[r] + cbs[0];
            skpb[i1] = aS1[r] + cbs[1];
        }
    }
}

// ---------------- ew1: sigmoid([h0n_t, h0n_{t-1}]@Wev1+b), parallel ---------
__global__ void ew1k(const _Float16* __restrict__ h0n, const float* __restrict__ Wev1,
                     const float* __restrict__ bev1, float* __restrict__ ew1p, int C, int t0) {
    const int w = threadIdx.x >> 6, lane = threadIdx.x & 63;
    const int wid = blockIdx.x * 4 + w;
    const int s = wid >> 5, rb = wid & 31;
    const int m = lane & 15, q = lane >> 4;
    float acc = 0.0f;
#pragma unroll
    for (int half = 0; half < 2; ++half) {
        const _Float16* base = h0n + ((size_t)(half ? s : s + 1) * 32 + rb) * 8192;
#pragma unroll
        for (int kc = 0; kc < 8; ++kc) {
            half8 ah = *(const half8*)&base[((kc * 4 + q) * 16 + m) * 8];
            half8 al = *(const half8*)&base[4096 + ((kc * 4 + q) * 16 + m) * 8];
            const float* wv = Wev1 + half * 256 + kc * 32 + q * 8;
#pragma unroll
            for (int j = 0; j < 8; ++j)
                acc += ((float)ah[j] + (float)al[j]) * wv[j];
        }
    }
    acc += __shfl_xor(acc, 16, 64);
    acc += __shfl_xor(acc, 32, 64);
    const int t = t0 + s;
    if (q == 0) {
        float e = (t > 0) ? fsigmoid(acc + bev1[0]) : 0.0f;
        ew1p[(size_t)(rb * 16 + m) * Tsz + t] = e;
    }
}

// ---------------- k1: layer-1 recurrence, persistent 32 blocks --------------
__global__ __launch_bounds__(512, 2) void k1(
    const float* __restrict__ in1b, const float* __restrict__ skpb,
    const float* __restrict__ ew1p,
    const _Float16* __restrict__ fA1, const _Float16* __restrict__ fR1,
    const float* __restrict__ brec1, const float* __restrict__ battn1,
    const float* __restrict__ tau1, const float* __restrict__ gamma1,
    const float* __restrict__ beta1, float* __restrict__ h1s, int C, int t0) {

    __shared__ _Float16 sAh[4096], sAl[4096];
    __shared__ _Float16 sW[65536];              // fA1 hi plane
    __shared__ float red[16][8][2];
    __shared__ float mv[16][2];

    const int tid = threadIdx.x;
    const int w = tid >> 6, lane = tid & 63;
    const int n16 = lane & 15, q = lane >> 4;
    const int rb = blockIdx.x;
    const int r0 = rb * 16;
    const int c0 = w * 16 + n16, c1 = c0 + 128;

    for (int i = tid; i < 8192; i += 512) {
        int rec = i >> 6, off = i & 63;
        ((int4*)sW)[i] = ((const int4*)(fA1 + (size_t)rec * 2 * 512))[off];
    }
    half8 rB[2][8][2];
#pragma unroll
    for (int t2 = 0; t2 < 2; ++t2) {
        const int tile = t2 ? w + 8 : w;
#pragma unroll
        for (int kc = 0; kc < 8; ++kc) {
#pragma unroll
            for (int sp = 0; sp < 2; ++sp)
                rB[t2][kc][sp] = *(const half8*)(fR1 + (((size_t)tile * 8 + kc) * 2 + sp) * 512 + lane * 8);
        }
    }
    float cbr[2], cba[2], ctau[2], cg[2], cb[2];
#pragma unroll
    for (int t2 = 0; t2 < 2; ++t2) {
        const int col = t2 ? c1 : c0;
        cbr[t2] = brec1[col]; cba[t2] = battn1[col];
        ctau[t2] = 0.1f / fminf(fmaxf(tau1[col], 0.1f), 10.0f);
        cg[t2] = gamma1[col]; cb[t2] = beta1[col];
    }
    float h1reg[2][4];
#pragma unroll
    for (int t2 = 0; t2 < 2; ++t2) {
        const int col = t2 ? c1 : c0;
#pragma unroll
        for (int r = 0; r < 4; ++r) {
            const int row = q * 4 + r;
            float hv = h1s[(size_t)(r0 + row) * Hsz + col];
            h1reg[t2][r] = hv;
            int idx = ((col >> 3) * 16 + row) * 8 + (col & 7);
            _Float16 h = (_Float16)hv;
            sAh[idx] = h;
            sAl[idx] = (_Float16)(hv - (float)h);
        }
    }
    __syncthreads();

    auto pw = [&](int row, int col, float v) {
        int idx = ((col >> 3) * 16 + row) * 8 + (col & 7);
        _Float16 h = (_Float16)v;
        sAh[idx] = h;
        sAl[idx] = (_Float16)(v - (float)h);
    };
    const _Float16* lo0 = fA1 + ((size_t)w * 8 * 2 + 1) * 512 + lane * 8;
    const _Float16* lo1 = fA1 + (((size_t)(w + 8) * 8) * 2 + 1) * 512 + lane * 8;

#pragma unroll 1
    for (int s = 0; s < C; ++s) {
        const int t = t0 + s;
        // early loads: in1 / skip / ew1
        float iv[2][4], sv[2][4], e1r[4];
#pragma unroll
        for (int r = 0; r < 4; ++r) {
            const int row = q * 4 + r;
            size_t i0 = ((size_t)s * Bsz + r0 + row) * Hsz + c0;
            size_t i1 = ((size_t)s * Bsz + r0 + row) * Hsz + c1;
            iv[0][r] = in1b[i0]; iv[1][r] = in1b[i1];
            sv[0][r] = skpb[i0]; sv[1][r] = skpb[i1];
            e1r[r] = ew1p[(size_t)(r0 + row) * Tsz + t];
        }
        // ---- mm_attn1: A = sA pair (h1_{t-1}) ----
        f32x4 aA0 = {0,0,0,0}, aA1 = {0,0,0,0};
        {
            half8 nl0 = *(const half8*)(lo0);
            half8 nl1 = *(const half8*)(lo1);
#pragma unroll
            for (int kc = 0; kc < 8; ++kc) {
                half8 cl0 = nl0, cl1 = nl1;
                if (kc < 7) {
                    nl0 = *(const half8*)(lo0 + (size_t)(kc + 1) * 2 * 512);
                    nl1 = *(const half8*)(lo1 + (size_t)(kc + 1) * 2 * 512);
                }
                half8 ah = *(const half8*)&sAh[((kc * 4 + q) * 16 + n16) * 8];
                half8 al = *(const half8*)&sAl[((kc * 4 + q) * 16 + n16) * 8];
                half8 bh0 = *(const half8*)&sW[((w * 8 + kc) * 512) + lane * 8];
                half8 bh1 = *(const half8*)&sW[(((w + 8) * 8 + kc) * 512) + lane * 8];
                aA0 = mfma16h(ah, bh0, aA0); aA1 = mfma16h(ah, bh1, aA1);
                aA0 = mfma16h(al, bh0, aA0); aA1 = mfma16h(al, bh1, aA1);
                aA0 = mfma16h(ah, cl0, aA0); aA1 = mfma16h(ah, cl1, aA1);
                aA0 = mfma16h(al, cl0, aA0); aA1 = mfma16h(al, cl1, aA1);
            }
        }
        __syncthreads();   // B1
#pragma unroll
        for (int r = 0; r < 4; ++r) {
            const int row = q * 4 + r;
            pw(row, c0, h1reg[0][r] * fsigmoid(aA0[r] + cba[0]));
            pw(row, c1, h1reg[1][r] * fsigmoid(aA1[r] + cba[1]));
        }
        __syncthreads();   // B2
        f32x4 aR0 = {0,0,0,0}, aR1 = {0,0,0,0};
#pragma unroll
        for (int kc = 0; kc < 8; ++kc) {
            half8 ah = *(const half8*)&sAh[((kc * 4 + q) * 16 + n16) * 8];
            half8 al = *(const half8*)&sAl[((kc * 4 + q) * 16 + n16) * 8];
            aR0 = mfma16h(ah, rB[0][kc][0], aR0); aR1 = mfma16h(ah, rB[1][kc][0], aR1);
            aR0 = mfma16h(al, rB[0][kc][0], aR0); aR1 = mfma16h(al, rB[1][kc][0], aR1);
            aR0 = mfma16h(ah, rB[0][kc][1], aR0); aR1 = mfma16h(ah, rB[1][kc][1], aR1);
            aR0 = mfma16h(al, rB[0][kc][1], aR0); aR1 = mfma16h(al, rB[1][kc][1], aR1);
        }
        float cell[2][4];
#pragma unroll
        for (int r = 0; r < 4; ++r) {
            float g0 = tanhf(aR0[r] + cbr[0]);
            float g1 = tanhf(aR1[r] + cbr[1]);
            float ef = 1.0f + e1r[r];
            cell[0][r] = h1reg[0][r] + ctau[0] * ef * (iv[0][r] + g0 - h1reg[0][r]);
            cell[1][r] = h1reg[1][r] + ctau[1] * ef * (iv[1][r] + g1 - h1reg[1][r]);
        }
#pragma unroll
        for (int r = 0; r < 4; ++r) {
            float pr = cell[0][r] + cell[1][r];
            float p2 = cell[0][r] * cell[0][r] + cell[1][r] * cell[1][r];
#pragma unroll
            for (int off = 1; off < 16; off <<= 1) {
                pr += __shfl_xor(pr, off, 64);
                p2 += __shfl_xor(p2, off, 64);
            }
            if (n16 == 0) { red[q * 4 + r][w][0] = pr; red[q * 4 + r][w][1] = p2; }
        }
        __syncthreads();   // B3
        if (tid < 16) {
            float S = 0.0f, Q2 = 0.0f;
#pragma unroll
            for (int wv = 0; wv < 8; ++wv) { S += red[tid][wv][0]; Q2 += red[tid][wv][1]; }
            float mu = S * (1.0f / 256.0f);
            float var = Q2 * (1.0f / 256.0f) - mu * mu;
            mv[tid][0] = mu;
            mv[tid][1] = 1.0f / sqrtf(var + 1e-5f);
        }
        __syncthreads();   // B4
#pragma unroll
        for (int r = 0; r < 4; ++r) {
            const int row = q * 4 + r;
            float h0v = (cell[0][r] - mv[row][0]) * mv[row][1] * cg[0] + cb[0] + sv[0][r];
            float h1v = (cell[1][r] - mv[row][0]) * mv[row][1] * cg[1] + cb[1] + sv[1][r];
            pw(row, c0, h0v); pw(row, c1, h1v);
            h1reg[0][r] = h0v; h1reg[1][r] = h1v;
        }
        __syncthreads();   // B5
    }
    // persist fp32 h1 state
#pragma unroll
    for (int t2 = 0; t2 < 2; ++t2) {
        const int col = t2 ? c1 : c0;
#pragma unroll
        for (int r = 0; r < 4; ++r)
            h1s[(size_t)(r0 + q * 4 + r) * Hsz + col] = h1reg[t2][r];
    }
}

// ---------------- out = h1_final @ Wout + bout ------------------------------
__global__ void outk(const float* __restrict__ h1s, const float* __restrict__ Wout,
                     const float* __restrict__ bout, float* __restrict__ outp) {
    const int w = threadIdx.x >> 6, lane = threadIdx.x & 63;
    const int b = blockIdx.x * 4 + w;
    float4 hv = *(const float4*)(h1s + (size_t)b * Hsz + lane * 4);
    float4 wv = *(const float4*)(Wout + lane * 4);
    float acc = hv.x * wv.x + hv.y * wv.y + hv.z * wv.z + hv.w * wv.w;
#pragma unroll
    for (int off = 1; off < 64; off <<= 1) acc += __shfl_xor(acc, off, 64);
    if (lane == 0) outp[b] = acc + bout[0];
}

extern "C" void kernel_launch(void* const* d_in, const int* in_sizes, int n_in,
                              void* d_out, int out_size, void* d_ws, size_t ws_size,
                              hipStream_t stream) {
    const float* x      = (const float*)d_in[0];
    const float* Win0   = (const float*)d_in[1];
    const float* bin0   = (const float*)d_in[2];
    const float* Wrec0  = (const float*)d_in[3];
    const float* brec0  = (const float*)d_in[4];
    const float* Wattn0 = (const float*)d_in[5];
    const float* battn0 = (const float*)d_in[6];
    const float* Wev0   = (const float*)d_in[7];
    const float* bev0   = (const float*)d_in[8];
    const float* tau0   = (const float*)d_in[9];
    const float* gamma0 = (const float*)d_in[10];
    const float* beta0  = (const float*)d_in[11];
    const float* Win1   = (const float*)d_in[12];
    const float* bin1   = (const float*)d_in[13];
    const float* Wrec1  = (const float*)d_in[14];
    const float* brec1  = (const float*)d_in[15];
    const float* Wattn1 = (const float*)d_in[16];
    const float* battn1 = (const float*)d_in[17];
    const float* Wev1   = (const float*)d_in[18];
    const float* bev1   = (const float*)d_in[19];
    const float* tau1   = (const float*)d_in[20];
    const float* gamma1 = (const float*)d_in[21];
    const float* beta1  = (const float*)d_in[22];
    const float* Wskip  = (const float*)d_in[23];
    const float* bskip  = (const float*)d_in[24];
    const float* Wout   = (const float*)d_in[25];
    const float* bout   = (const float*)d_in[26];

    float* outp = (float*)d_out;
    float* ew0p = outp + Bsz;                       // ew0 [B,T]
    float* ew1p = ew0p + (size_t)Bsz * Tsz;         // ew1 [B,T]

    // ---- workspace layout ----
    // fragments (7 arrays, fp16 split-2) | h0n ((C+1)*512KB) | in1b | skpb | h1s
    _Float16* p = (_Float16*)d_ws;
    _Float16* fA0 = p; p += 131072;
    _Float16* fR0 = p; p += 131072;
    _Float16* fA1 = p; p += 131072;
    _Float16* fR1 = p; p += 131072;
    _Float16* fI1 = p; p += 131072;
    _Float16* fS1 = p; p += 131072;
    _Float16* fI0 = p; p += 16384;
    size_t frag_bytes = (size_t)(6 * 131072 + 16384) * 2;

    int C = 256;
    while (C > 16) {
        size_t need = frag_bytes + (size_t)(C + 1) * 524288        // h0n
                    + (size_t)C * 524288 * 2                        // in1b + skpb
                    + 524288;                                       // h1s
        if (need <= ws_size) break;
        C >>= 1;
    }
    char* q = (char*)d_ws + frag_bytes;
    _Float16* h0n = (_Float16*)q;                 q += (size_t)(C + 1) * 524288;
    float* in1b = (float*)q;                      q += (size_t)C * 524288;
    float* skpb = (float*)q;                      q += (size_t)C * 524288;
    float* h1s = (float*)q;
    (void)in_sizes; (void)n_in; (void)out_size;

    hipMemsetAsync(h0n + (size_t)C * 32 * 8192, 0, 524288, stream);   // h0_{-1} = 0
    hipMemsetAsync(h1s, 0, 524288, stream);                            // h1_{-1} = 0

    ew0k<<<(Bsz * Tsz) / 256, 256, 0, stream>>>(x, Wev0, bev0, ew0p);
    prep_frag<<<16 * 8, 64, 0, stream>>>(Wattn0, fA0, 8);
    prep_frag<<<16 * 8, 64, 0, stream>>>(Wrec0,  fR0, 8);
    prep_frag<<<16 * 8, 64, 0, stream>>>(Wattn1, fA1, 8);
    prep_frag<<<16 * 8, 64, 0, stream>>>(Wrec1,  fR1, 8);
    prep_frag<<<16 * 8, 64, 0, stream>>>(Win1,   fI1, 8);
    prep_frag<<<16 * 8, 64, 0, stream>>>(Wskip,  fS1, 8);
    prep_frag<<<16 * 1, 64, 0, stream>>>(Win0,   fI0, 1);

    const int nch = Tsz / C;
    for (int c = 0; c < nch; ++c) {
        const int t0 = c * C;
        k0<<<32, 512, 0, stream>>>(x, ew0p, fA0, fR0, fI0,
                                   bin0, brec0, battn0, tau0, gamma0, beta0,
                                   h0n, C, t0);
        ew1k<<<C * 8, 256, 0, stream>>>(h0n, Wev1, bev1, ew1p, C, t0);
        kb<<<C * 4, 512, 0, stream>>>(h0n, fI1, fS1, bin1, bskip, in1b, skpb, C);
        k1<<<32, 512, 0, stream>>>(in1b, skpb, ew1p, fA1, fR1,
                                   brec1, battn1, tau1, gamma1, beta1,
                                   h1s, C, t0);
    }
    outk<<<Bsz / 4, 256, 0, stream>>>(h1s, Wout, bout, outp);
}